// Round 6
// baseline (1282.025 us; speedup 1.0000x reference)
//
#include <hip/hip_runtime.h>

#define N_VUL  100000
#define N_SRC  50000
#define N_EDGE 500000
#define DIM    128

// ===========================================================================
// TIER S (ws >= 44.5 MB): single-int partition + fused LDS-accumulator agg.
//   gcount : NB ints        bucket counts        ws[0..NB)
//   cbase  : NB+1 ints      excl scan            ws[2048..]
//   cursor : NB ints        partition cursors    ws[4096..]
//   ss2p   : 3*N_EDGE ints  bucket-grouped packed edges (src|dl<<16|r<<22)
//   xb     : 3*N_SRC*DIM ushort  bf16 x
// Bucket = dst >> 6 (64 dsts/bucket, NB = 1563 buckets, shared by relations).
// TIER B (ws >= 7.2 MB): R3 fused f32 path.  TIER C: R2 sequential path.
// ===========================================================================

#define DSH  6
#define NDB  (1 << DSH)                         // 64 dsts per bucket
#define NB   ((N_VUL + NDB - 1) >> DSH)         // 1563
#define PART_E  4096
#define PART_BLOCKS ((3 * N_EDGE + PART_E - 1) / PART_E)   // 367

#define CVT_Q      (N_SRC * DIM / 4)            // 1.6M float4 per relation
#define CVT_BLOCKS (3 * CVT_Q / 256)            // 18750 (exact)

__device__ __forceinline__ unsigned short f2bf(float f) {
    unsigned u = __float_as_uint(f);
    unsigned r = (u + 0x7FFFu + ((u >> 16) & 1u)) >> 16;   // RNE
    return (unsigned short)r;
}
__device__ __forceinline__ float bf2f(unsigned short h) {
    return __uint_as_float(((unsigned)h) << 16);
}

__global__ void zero_i_kernel(int* __restrict__ p, int n) {
    int i = blockIdx.x * blockDim.x + threadIdx.x;
    if (i < n) p[i] = 0;
}

// ------------------------- TIER S kernels ----------------------------------

// Heterogeneous: blocks [0,CVT_BLOCKS) convert f32->bf16; the rest histogram
// the NB coarse buckets via per-block LDS hist.
__global__ void cvt_chist_kernel(const float4* __restrict__ x0, const float4* __restrict__ x1,
                                 const float4* __restrict__ x2, ushort4* __restrict__ xb4,
                                 const int* __restrict__ d0, const int* __restrict__ d1,
                                 const int* __restrict__ d2, int* __restrict__ gcount) {
    __shared__ int lh[NB];
    int b = blockIdx.x;
    if (b < CVT_BLOCKS) {
        int i = b * 256 + threadIdx.x;
        int r = i / CVT_Q;
        int e = i - r * CVT_Q;
        float4 v = ((r == 0) ? x0 : (r == 1) ? x1 : x2)[e];
        ushort4 o;
        o.x = f2bf(v.x); o.y = f2bf(v.y); o.z = f2bf(v.z); o.w = f2bf(v.w);
        xb4[i] = o;
    } else {
        int tid = threadIdx.x;
        for (int j = tid; j < NB; j += 256) lh[j] = 0;
        __syncthreads();
        int e0 = (b - CVT_BLOCKS) * PART_E;
        #pragma unroll
        for (int k = 0; k < PART_E / 256; ++k) {
            int i = e0 + k * 256 + tid;
            if (i < 3 * N_EDGE) {
                int r = (i >= 2 * N_EDGE) ? 2 : (i >= N_EDGE) ? 1 : 0;
                int e = i - r * N_EDGE;
                const int* dp = (r == 0) ? d0 : (r == 1) ? d1 : d2;
                atomicAdd(&lh[dp[e] >> DSH], 1);
            }
        }
        __syncthreads();
        for (int j = tid; j < NB; j += 256)
            if (lh[j]) atomicAdd(&gcount[j], lh[j]);
    }
}

// Exclusive scan of gcount[NB] -> cbase[NB+1]; cursor = cbase. One block, 256 thr.
__global__ void cscan_kernel(const int* __restrict__ gcount, int* __restrict__ cbase,
                             int* __restrict__ cursor) {
    __shared__ int wsum[4];
    const int tid = threadIdx.x;
    const int lane = tid & 63, wid = tid >> 6;
    int vals[7]; int tsum = 0;
    int idx0 = tid * 7;
    #pragma unroll
    for (int k = 0; k < 7; ++k) {
        vals[k] = (idx0 + k < NB) ? gcount[idx0 + k] : 0;
        tsum += vals[k];
    }
    int s = tsum;
    #pragma unroll
    for (int off = 1; off < 64; off <<= 1) {
        int t = __shfl_up(s, off);
        if (lane >= off) s += t;
    }
    if (lane == 63) wsum[wid] = s;
    __syncthreads();
    if (tid == 0) {
        int a = 0;
        #pragma unroll
        for (int j = 0; j < 4; ++j) { int t = wsum[j]; wsum[j] = a; a += t; }
    }
    __syncthreads();
    int run = (s - tsum) + wsum[wid];
    #pragma unroll
    for (int k = 0; k < 7; ++k) {
        if (idx0 + k < NB) { cbase[idx0 + k] = run; cursor[idx0 + k] = run; }
        run += vals[k];
    }
    if (tid == 255) cbase[NB] = run;
}

// Partition edges into NB buckets; packed payload int, LDS-staged so global
// writes flush as contiguous per-bucket runs.
__global__ void __launch_bounds__(256) partition_kernel(
        const int* __restrict__ s0, const int* __restrict__ d0,
        const int* __restrict__ s1, const int* __restrict__ d1,
        const int* __restrict__ s2, const int* __restrict__ d2,
        int* __restrict__ cursor, int* __restrict__ ss2p) {
    __shared__ int hist[NB];
    __shared__ int lbase[NB];
    __shared__ int gbase[NB];
    __shared__ int stage_p[PART_E];
    __shared__ int stage_b[PART_E];
    __shared__ int wsum[4];
    __shared__ int s_vtot;

    const int tid = threadIdx.x;
    const int lane = tid & 63, wid = tid >> 6;
    for (int j = tid; j < NB; j += 256) hist[j] = 0;
    __syncthreads();

    const int e0 = blockIdx.x * PART_E;
    int myp[PART_E / 256], mybr[PART_E / 256];
    #pragma unroll
    for (int k = 0; k < PART_E / 256; ++k) {
        int i = e0 + k * 256 + tid;
        if (i < 3 * N_EDGE) {
            int r = (i >= 2 * N_EDGE) ? 2 : (i >= N_EDGE) ? 1 : 0;
            int e = i - r * N_EDGE;
            const int* sp = (r == 0) ? s0 : (r == 1) ? s1 : s2;
            const int* dp = (r == 0) ? d0 : (r == 1) ? d1 : d2;
            int d = dp[e];
            int bkt = d >> DSH;
            int rank = atomicAdd(&hist[bkt], 1);
            myp[k]  = sp[e] | ((d & (NDB - 1)) << 16) | (r << 22);
            mybr[k] = rank | (bkt << 12);
        } else {
            mybr[k] = -1;
        }
    }
    __syncthreads();

    // parallel exclusive scan of hist[NB] -> lbase[NB] (hist preserved)
    {
        int vals[7]; int tsum = 0;
        int idx0 = tid * 7;
        #pragma unroll
        for (int k = 0; k < 7; ++k) {
            vals[k] = (idx0 + k < NB) ? hist[idx0 + k] : 0;
            tsum += vals[k];
        }
        int s = tsum;
        #pragma unroll
        for (int off = 1; off < 64; off <<= 1) {
            int t = __shfl_up(s, off);
            if (lane >= off) s += t;
        }
        if (lane == 63) wsum[wid] = s;
        __syncthreads();
        if (tid == 0) {
            int a = 0;
            #pragma unroll
            for (int j = 0; j < 4; ++j) { int t = wsum[j]; wsum[j] = a; a += t; }
        }
        __syncthreads();
        int run = (s - tsum) + wsum[wid];
        #pragma unroll
        for (int k = 0; k < 7; ++k) {
            if (idx0 + k < NB) lbase[idx0 + k] = run;
            run += vals[k];
        }
        if (tid == 255) s_vtot = run;
    }
    __syncthreads();

    for (int j = tid; j < NB; j += 256)
        if (hist[j] > 0) gbase[j] = atomicAdd(&cursor[j], hist[j]);
    __syncthreads();

    #pragma unroll
    for (int k = 0; k < PART_E / 256; ++k) {
        if (mybr[k] >= 0) {
            int bkt  = mybr[k] >> 12;
            int rank = mybr[k] & 0xFFF;
            int slot = lbase[bkt] + rank;
            stage_p[slot] = myp[k];
            stage_b[slot] = bkt;
        }
    }
    __syncthreads();

    const int vtot = s_vtot;
    for (int j = tid; j < vtot; j += 256) {
        int bkt = stage_b[j];
        ss2p[gbase[bkt] + (j - lbase[bkt])] = stage_p[j];
    }
}

// Fused degree-count + gather + scaled LDS accumulate + writeout.
// One block per bucket (64 dsts). Accumulator layout permuted:
// col c stored at d*128 + (c&3)*32 + (c>>2)  -> ds_add conflict-free.
__global__ void __launch_bounds__(256) agg_kernel(
        const unsigned short* __restrict__ xb, const int* __restrict__ cbase,
        const int* __restrict__ ss2p, float* __restrict__ out) {
    __shared__ float accum[NDB * DIM];     // 32 KB
    __shared__ int   hist[3 * NDB];
    __shared__ float scale[3 * NDB];

    const int tid = threadIdx.x;
    const int b   = blockIdx.x;
    const int dbase = b << DSH;
    int dcount = N_VUL - dbase; if (dcount > NDB) dcount = NDB;

    const int beg = cbase[b];
    const int end = cbase[b + 1];

    for (int j = tid; j < 3 * NDB; j += 256) hist[j] = 0;
    #pragma unroll
    for (int k = 0; k < NDB * DIM / 256; ++k) accum[k * 256 + tid] = 0.f;
    __syncthreads();

    // pass A: per-(r,d) degree count
    for (int j = beg + tid; j < end; j += 256) {
        int p = ss2p[j];
        atomicAdd(&hist[((p >> 22) & 3) * NDB + ((p >> 16) & (NDB - 1))], 1);
    }
    __syncthreads();
    if (tid < 3 * NDB) {
        int c = hist[tid];
        scale[tid] = 1.0f / (3.0f * (float)(c > 0 ? c : 1));
    }
    __syncthreads();

    // pass B: gather + scaled accumulate (32 lanes/edge, 2-edge ILP)
    const int lane = tid & 31;
    const int half = tid >> 5;              // 0..7
    for (int j0 = beg; j0 < end; j0 += 16) {
        int je1 = j0 + half;
        int je2 = j0 + 8 + half;
        int p1 = (je1 < end) ? ss2p[je1] : -1;
        int p2 = (je2 < end) ? ss2p[je2] : -1;
        ushort4 a1, a2; float sc1 = 0.f, sc2 = 0.f; int d1 = 0, d2 = 0;
        if (p1 >= 0) {
            int s = p1 & 0xFFFF; int r = (p1 >> 22) & 3; d1 = (p1 >> 16) & (NDB - 1);
            sc1 = scale[r * NDB + d1];
            a1 = ((const ushort4*)(xb + ((size_t)r * N_SRC + s) * DIM))[lane];
        }
        if (p2 >= 0) {
            int s = p2 & 0xFFFF; int r = (p2 >> 22) & 3; d2 = (p2 >> 16) & (NDB - 1);
            sc2 = scale[r * NDB + d2];
            a2 = ((const ushort4*)(xb + ((size_t)r * N_SRC + s) * DIM))[lane];
        }
        if (p1 >= 0) {
            float* ac = accum + d1 * DIM;
            atomicAdd(ac +      lane, bf2f(a1.x) * sc1);
            atomicAdd(ac + 32 + lane, bf2f(a1.y) * sc1);
            atomicAdd(ac + 64 + lane, bf2f(a1.z) * sc1);
            atomicAdd(ac + 96 + lane, bf2f(a1.w) * sc1);
        }
        if (p2 >= 0) {
            float* ac = accum + d2 * DIM;
            atomicAdd(ac +      lane, bf2f(a2.x) * sc2);
            atomicAdd(ac + 32 + lane, bf2f(a2.y) * sc2);
            atomicAdd(ac + 64 + lane, bf2f(a2.z) * sc2);
            atomicAdd(ac + 96 + lane, bf2f(a2.w) * sc2);
        }
    }
    __syncthreads();

    // writeout: un-permute, coalesced float4 stores
    int total4 = dcount * 32;
    for (int idx = tid; idx < total4; idx += 256) {
        int d = idx >> 5, q = idx & 31;
        const float* ac = accum + d * DIM;
        float4 f;
        f.x = ac[q]; f.y = ac[32 + q]; f.z = ac[64 + q]; f.w = ac[96 + q];
        ((float4*)(out + (size_t)(dbase + d) * DIM))[q] = f;
    }
}

// ------------------------- TIER B / C kernels ------------------------------

__global__ void count3_kernel(const int* __restrict__ d0, const int* __restrict__ d1,
                              const int* __restrict__ d2, int* __restrict__ rp) {
    int i = blockIdx.x * blockDim.x + threadIdx.x;
    if (i >= 3 * N_EDGE) return;
    int r = (i >= 2 * N_EDGE) ? 2 : (i >= N_EDGE) ? 1 : 0;
    int e = i - r * N_EDGE;
    const int* d = (r == 0) ? d0 : (r == 1) ? d1 : d2;
    atomicAdd(&rp[r * N_VUL + d[e]], 1);
}

__global__ void scan_local_kernel(int* __restrict__ rp, int* __restrict__ bsum, int n) {
    __shared__ int wsum[4];
    const int tid  = threadIdx.x;
    const int lane = tid & 63;
    const int wid  = tid >> 6;
    int idx = blockIdx.x * 1024 + tid * 4;
    int4 v = make_int4(0, 0, 0, 0);
    if (idx + 3 < n)      v = *(const int4*)(rp + idx);
    else {
        if (idx + 0 < n) v.x = rp[idx + 0];
        if (idx + 1 < n) v.y = rp[idx + 1];
        if (idx + 2 < n) v.z = rp[idx + 2];
        if (idx + 3 < n) v.w = rp[idx + 3];
    }
    int tsum = v.x + v.y + v.z + v.w;
    int s = tsum;
    #pragma unroll
    for (int off = 1; off < 64; off <<= 1) {
        int t = __shfl_up(s, off);
        if (lane >= off) s += t;
    }
    if (lane == 63) wsum[wid] = s;
    __syncthreads();
    if (tid == 0) {
        int a = 0;
        #pragma unroll
        for (int j = 0; j < 4; ++j) { int t = wsum[j]; wsum[j] = a; a += t; }
        bsum[blockIdx.x] = a;
    }
    __syncthreads();
    int excl = (s - tsum) + wsum[wid];
    int4 o;
    o.x = excl; o.y = o.x + v.x; o.z = o.y + v.y; o.w = o.z + v.z;
    if (idx + 3 < n)      *(int4*)(rp + idx) = o;
    else {
        if (idx + 0 < n) rp[idx + 0] = o.x;
        if (idx + 1 < n) rp[idx + 1] = o.y;
        if (idx + 2 < n) rp[idx + 2] = o.z;
        if (idx + 3 < n) rp[idx + 3] = o.w;
    }
}

__global__ void scan_bsum_kernel(int* __restrict__ bsum, int nb) {
    __shared__ int sh[512];
    int tid = threadIdx.x;
    int v = (tid < nb) ? bsum[tid] : 0;
    sh[tid] = v;
    __syncthreads();
    #pragma unroll
    for (int off = 1; off < 512; off <<= 1) {
        int t = 0;
        if (tid >= off) t = sh[tid - off];
        __syncthreads();
        sh[tid] += t;
        __syncthreads();
    }
    if (tid < nb) bsum[tid] = sh[tid] - v;
}

__global__ void add_off_kernel(int4* __restrict__ rp4, const int* __restrict__ bsum, int n4) {
    int i = blockIdx.x * blockDim.x + threadIdx.x;
    if (i >= n4) return;
    int off = bsum[i >> 8];
    int4 v = rp4[i];
    v.x += off; v.y += off; v.z += off; v.w += off;
    rp4[i] = v;
}

__global__ void scatter3_kernel(const int* __restrict__ s0, const int* __restrict__ d0,
                                const int* __restrict__ s1, const int* __restrict__ d1,
                                const int* __restrict__ s2, const int* __restrict__ d2,
                                int* __restrict__ rp, int* __restrict__ ss) {
    int i = blockIdx.x * blockDim.x + threadIdx.x;
    if (i >= 3 * N_EDGE) return;
    int r = (i >= 2 * N_EDGE) ? 2 : (i >= N_EDGE) ? 1 : 0;
    int e = i - r * N_EDGE;
    const int* sp = (r == 0) ? s0 : (r == 1) ? s1 : s2;
    const int* dp = (r == 0) ? d0 : (r == 1) ? d1 : d2;
    int pos = atomicAdd(&rp[r * N_VUL + dp[e]], 1);
    ss[pos] = sp[e];
}

__global__ void gather3_kernel(const float* __restrict__ x0, const float* __restrict__ x1,
                               const float* __restrict__ x2,
                               const int* __restrict__ rp, const int* __restrict__ ss,
                               float* __restrict__ out) {
    int t    = blockIdx.x * blockDim.x + threadIdx.x;
    int v    = t >> 5;
    int lane = t & 31;
    if (v >= N_VUL) return;
    float4 res = make_float4(0.f, 0.f, 0.f, 0.f);
    #pragma unroll
    for (int r = 0; r < 3; ++r) {
        const float* x = (r == 0) ? x0 : (r == 1) ? x1 : x2;
        int g   = r * N_VUL + v;
        int end = rp[g];
        int beg = (g == 0) ? 0 : rp[g - 1];
        float4 acc = make_float4(0.f, 0.f, 0.f, 0.f);
        for (int base = beg; base < end; base += 32) {
            int j  = base + lane;
            int sv = (j < end) ? ss[j] : 0;
            int m  = end - base;
            if (m > 32) m = 32;
            for (int k = 0; k < m; ++k) {
                int s = __shfl(sv, k, 32);
                float4 xv = ((const float4*)(x + (size_t)s * DIM))[lane];
                acc.x += xv.x; acc.y += xv.y; acc.z += xv.z; acc.w += xv.w;
            }
        }
        int deg = end - beg;
        float sc = 1.0f / (3.0f * (float)(deg > 0 ? deg : 1));
        res.x += acc.x * sc; res.y += acc.y * sc;
        res.z += acc.z * sc; res.w += acc.w * sc;
    }
    ((float4*)(out + (size_t)v * DIM))[lane] = res;
}

__global__ void count_kernel(const int* __restrict__ dst, int* __restrict__ cnt, int n) {
    int i = blockIdx.x * blockDim.x + threadIdx.x;
    if (i < n) atomicAdd(&cnt[dst[i]], 1);
}

__global__ void scan_kernel(int* __restrict__ rp, int n) {
    __shared__ int warp_sums[16];
    __shared__ int s_carry;
    const int tid  = threadIdx.x;
    const int lane = tid & 63;
    const int wid  = tid >> 6;
    if (tid == 0) s_carry = 0;
    __syncthreads();
    for (int base = 0; base < n; base += 4096) {
        int idx = base + tid * 4;
        int4 v = make_int4(0, 0, 0, 0);
        if (idx + 3 < n) v = *(const int4*)(rp + idx);
        else {
            if (idx + 0 < n) v.x = rp[idx + 0];
            if (idx + 1 < n) v.y = rp[idx + 1];
            if (idx + 2 < n) v.z = rp[idx + 2];
            if (idx + 3 < n) v.w = rp[idx + 3];
        }
        int tsum = v.x + v.y + v.z + v.w;
        int s = tsum;
        #pragma unroll
        for (int off = 1; off < 64; off <<= 1) {
            int t = __shfl_up(s, off);
            if (lane >= off) s += t;
        }
        if (lane == 63) warp_sums[wid] = s;
        __syncthreads();
        if (tid < 16) {
            int ws = warp_sums[tid];
            #pragma unroll
            for (int off = 1; off < 16; off <<= 1) {
                int t = __shfl_up(ws, off);
                if (tid >= off) ws += t;
            }
            warp_sums[tid] = ws;
        }
        __syncthreads();
        int carry = s_carry;
        int excl  = s - tsum + (wid > 0 ? warp_sums[wid - 1] : 0) + carry;
        int4 o;
        o.x = excl; o.y = o.x + v.x; o.z = o.y + v.y; o.w = o.z + v.z;
        if (idx + 3 < n) *(int4*)(rp + idx) = o;
        else {
            if (idx + 0 < n) rp[idx + 0] = o.x;
            if (idx + 1 < n) rp[idx + 1] = o.y;
            if (idx + 2 < n) rp[idx + 2] = o.z;
            if (idx + 3 < n) rp[idx + 3] = o.w;
        }
        __syncthreads();
        if (tid == 0) s_carry = carry + warp_sums[15];
        __syncthreads();
    }
}

__global__ void scatter_kernel(const int* __restrict__ src, const int* __restrict__ dst,
                               int* __restrict__ rp, int* __restrict__ ss, int n) {
    int i = blockIdx.x * blockDim.x + threadIdx.x;
    if (i < n) {
        int pos = atomicAdd(&rp[dst[i]], 1);
        ss[pos] = src[i];
    }
}

template <bool ACC>
__global__ void gather_kernel(const float* __restrict__ x, const int* __restrict__ rp,
                              const int* __restrict__ ss, float* __restrict__ out) {
    int t    = blockIdx.x * blockDim.x + threadIdx.x;
    int v    = t >> 5;
    int lane = t & 31;
    if (v >= N_VUL) return;
    int end = rp[v];
    int beg = (v == 0) ? 0 : rp[v - 1];
    float4 acc = make_float4(0.f, 0.f, 0.f, 0.f);
    for (int base = beg; base < end; base += 32) {
        int j  = base + lane;
        int sv = (j < end) ? ss[j] : 0;
        int m  = end - base;
        if (m > 32) m = 32;
        for (int k = 0; k < m; ++k) {
            int s = __shfl(sv, k, 32);
            float4 xv = ((const float4*)(x + (size_t)s * DIM))[lane];
            acc.x += xv.x; acc.y += xv.y; acc.z += xv.z; acc.w += xv.w;
        }
    }
    int deg = end - beg;
    float sc = 1.0f / (3.0f * (float)(deg > 0 ? deg : 1));
    float4 res;
    res.x = acc.x * sc; res.y = acc.y * sc; res.z = acc.z * sc; res.w = acc.w * sc;
    float4* o = (float4*)(out + (size_t)v * DIM) + lane;
    if (ACC) {
        float4 prev = *o;
        res.x += prev.x; res.y += prev.y; res.z += prev.z; res.w += prev.w;
    }
    *o = res;
}

// ---------------------------------------------------------------------------
extern "C" void kernel_launch(void* const* d_in, const int* in_sizes, int n_in,
                              void* d_out, int out_size, void* d_ws, size_t ws_size,
                              hipStream_t stream) {
    const float* x[3]   = { (const float*)d_in[0], (const float*)d_in[1], (const float*)d_in[2] };
    const int*   src[3] = { (const int*)d_in[3],   (const int*)d_in[5],   (const int*)d_in[7] };
    const int*   dst[3] = { (const int*)d_in[4],   (const int*)d_in[6],   (const int*)d_in[8] };
    float* out = (float*)d_out;

    const int B = 256;
    const int n_rp     = 3 * N_VUL;
    const int n_chunks = (n_rp + 1023) / 1024;
    const int n_rp4    = n_rp / 4;

    // Tier S layout (ints): gcount@0 | cbase@2048 | cursor@4096 | ss2p@6144 | xb
    const size_t S_INTS = 6144 + (size_t)3 * N_EDGE;
    const size_t S_WS   = S_INTS * 4 + (size_t)3 * N_SRC * DIM * sizeof(short);  // ~44.4 MB
    const size_t INT_WS = (size_t)(n_rp + 3 * N_EDGE + 512) * sizeof(int);       // 7.2 MB

    if (ws_size >= S_WS) {
        int* gcount = (int*)d_ws;
        int* cbase  = gcount + 2048;
        int* cursor = gcount + 4096;
        int* ss2p   = gcount + 6144;
        unsigned short* xb = (unsigned short*)(ss2p + 3 * N_EDGE);

        zero_i_kernel<<<(NB + B - 1) / B, B, 0, stream>>>(gcount, NB);
        cvt_chist_kernel<<<CVT_BLOCKS + PART_BLOCKS, B, 0, stream>>>(
            (const float4*)x[0], (const float4*)x[1], (const float4*)x[2], (ushort4*)xb,
            dst[0], dst[1], dst[2], gcount);
        cscan_kernel<<<1, B, 0, stream>>>(gcount, cbase, cursor);
        partition_kernel<<<PART_BLOCKS, B, 0, stream>>>(
            src[0], dst[0], src[1], dst[1], src[2], dst[2], cursor, ss2p);
        agg_kernel<<<NB, B, 0, stream>>>(xb, cbase, ss2p, out);
    } else if (ws_size >= INT_WS) {
        int* rp   = (int*)d_ws;
        int* ss   = rp + n_rp;
        int* bsum = ss + 3 * N_EDGE;

        zero_i_kernel<<<(n_rp + B - 1) / B, B, 0, stream>>>(rp, n_rp);
        count3_kernel<<<(3 * N_EDGE + B - 1) / B, B, 0, stream>>>(dst[0], dst[1], dst[2], rp);
        scan_local_kernel<<<n_chunks, B, 0, stream>>>(rp, bsum, n_rp);
        scan_bsum_kernel<<<1, 512, 0, stream>>>(bsum, n_chunks);
        add_off_kernel<<<(n_rp4 + B - 1) / B, B, 0, stream>>>((int4*)rp, bsum, n_rp4);
        scatter3_kernel<<<(3 * N_EDGE + B - 1) / B, B, 0, stream>>>(
            src[0], dst[0], src[1], dst[1], src[2], dst[2], rp, ss);
        gather3_kernel<<<(N_VUL * 32 + B - 1) / B, B, 0, stream>>>(
            x[0], x[1], x[2], rp, ss, out);
    } else {
        int* rp = (int*)d_ws;
        int* ss = rp + N_VUL;
        const int g_node = (N_VUL + B - 1) / B;
        const int g_edge = (N_EDGE + B - 1) / B;
        const int g_gath = (N_VUL * 32 + B - 1) / B;
        for (int r = 0; r < 3; ++r) {
            zero_i_kernel<<<g_node, B, 0, stream>>>(rp, N_VUL);
            count_kernel<<<g_edge, B, 0, stream>>>(dst[r], rp, N_EDGE);
            scan_kernel<<<1, 1024, 0, stream>>>(rp, N_VUL);
            scatter_kernel<<<g_edge, B, 0, stream>>>(src[r], dst[r], rp, ss, N_EDGE);
            if (r == 0) gather_kernel<false><<<g_gath, B, 0, stream>>>(x[r], rp, ss, out);
            else        gather_kernel<true ><<<g_gath, B, 0, stream>>>(x[r], rp, ss, out);
        }
    }
}

// Round 7
// 329.485 us; speedup vs baseline: 3.8910x; 3.8910x over previous
//
#include <hip/hip_runtime.h>

#define N_VUL  100000
#define N_SRC  50000
#define N_EDGE 500000
#define DIM    128

// ===========================================================================
// TIER S (ws >= 44.5 MB): packed partition + fused in-LDS sort + register
// gather (NO f32 atomics anywhere -- R6 showed ds_atomic_add_f32 is ~17x
// slower than register accumulation at this edge density).
//   gcount : NB ints        bucket counts        ws[0..NB)
//   cbase  : NB+1 ints      excl scan            ws[2048..]
//   cursor : NB ints        partition cursors    ws[4096..]
//   ss2p   : 3*N_EDGE ints  bucket-grouped packed edges (src|dl<<16|r<<22)
//   xb     : 3*N_SRC*DIM ushort  bf16 x
// Bucket = dst >> 6 (64 dsts/bucket, NB = 1563, shared by all relations).
// TIER B (ws >= 7.2 MB): R3 fused f32 path.  TIER C: R2 sequential path.
// ===========================================================================

#define DSH  6
#define NDB  (1 << DSH)                         // 64 dsts per bucket
#define NB   ((N_VUL + NDB - 1) >> DSH)         // 1563
#define NK   (3 * NDB)                          // 192 (r,dl) keys
#define CAP  2048                               // LDS sorted-edge capacity
#define PART_E  4096
#define PART_BLOCKS ((3 * N_EDGE + PART_E - 1) / PART_E)   // 367

#define CVT_Q      (N_SRC * DIM / 4)            // 1.6M float4 per relation
#define CVT_BLOCKS (3 * CVT_Q / 256)            // 18750 (exact)

__device__ __forceinline__ unsigned short f2bf(float f) {
    unsigned u = __float_as_uint(f);
    unsigned r = (u + 0x7FFFu + ((u >> 16) & 1u)) >> 16;   // RNE
    return (unsigned short)r;
}
__device__ __forceinline__ float bf2f(unsigned short h) {
    return __uint_as_float(((unsigned)h) << 16);
}

__global__ void zero_i_kernel(int* __restrict__ p, int n) {
    int i = blockIdx.x * blockDim.x + threadIdx.x;
    if (i < n) p[i] = 0;
}

// ------------------------- TIER S kernels ----------------------------------

// Heterogeneous: blocks [0,CVT_BLOCKS) convert f32->bf16; the rest histogram
// the NB coarse buckets via per-block LDS hist. (verified R6)
__global__ void cvt_chist_kernel(const float4* __restrict__ x0, const float4* __restrict__ x1,
                                 const float4* __restrict__ x2, ushort4* __restrict__ xb4,
                                 const int* __restrict__ d0, const int* __restrict__ d1,
                                 const int* __restrict__ d2, int* __restrict__ gcount) {
    __shared__ int lh[NB];
    int b = blockIdx.x;
    if (b < CVT_BLOCKS) {
        int i = b * 256 + threadIdx.x;
        int r = i / CVT_Q;
        int e = i - r * CVT_Q;
        float4 v = ((r == 0) ? x0 : (r == 1) ? x1 : x2)[e];
        ushort4 o;
        o.x = f2bf(v.x); o.y = f2bf(v.y); o.z = f2bf(v.z); o.w = f2bf(v.w);
        xb4[i] = o;
    } else {
        int tid = threadIdx.x;
        for (int j = tid; j < NB; j += 256) lh[j] = 0;
        __syncthreads();
        int e0 = (b - CVT_BLOCKS) * PART_E;
        #pragma unroll
        for (int k = 0; k < PART_E / 256; ++k) {
            int i = e0 + k * 256 + tid;
            if (i < 3 * N_EDGE) {
                int r = (i >= 2 * N_EDGE) ? 2 : (i >= N_EDGE) ? 1 : 0;
                int e = i - r * N_EDGE;
                const int* dp = (r == 0) ? d0 : (r == 1) ? d1 : d2;
                atomicAdd(&lh[dp[e] >> DSH], 1);
            }
        }
        __syncthreads();
        for (int j = tid; j < NB; j += 256)
            if (lh[j]) atomicAdd(&gcount[j], lh[j]);
    }
}

// Exclusive scan of gcount[NB] -> cbase[NB+1]; cursor = cbase. (verified R6)
__global__ void cscan_kernel(const int* __restrict__ gcount, int* __restrict__ cbase,
                             int* __restrict__ cursor) {
    __shared__ int wsum[4];
    const int tid = threadIdx.x;
    const int lane = tid & 63, wid = tid >> 6;
    int vals[7]; int tsum = 0;
    int idx0 = tid * 7;
    #pragma unroll
    for (int k = 0; k < 7; ++k) {
        vals[k] = (idx0 + k < NB) ? gcount[idx0 + k] : 0;
        tsum += vals[k];
    }
    int s = tsum;
    #pragma unroll
    for (int off = 1; off < 64; off <<= 1) {
        int t = __shfl_up(s, off);
        if (lane >= off) s += t;
    }
    if (lane == 63) wsum[wid] = s;
    __syncthreads();
    if (tid == 0) {
        int a = 0;
        #pragma unroll
        for (int j = 0; j < 4; ++j) { int t = wsum[j]; wsum[j] = a; a += t; }
    }
    __syncthreads();
    int run = (s - tsum) + wsum[wid];
    #pragma unroll
    for (int k = 0; k < 7; ++k) {
        if (idx0 + k < NB) { cbase[idx0 + k] = run; cursor[idx0 + k] = run; }
        run += vals[k];
    }
    if (tid == 255) cbase[NB] = run;
}

// Partition edges into NB buckets; packed payload int, LDS-staged so global
// writes flush as contiguous per-bucket runs. (verified R6)
__global__ void __launch_bounds__(256) partition_kernel(
        const int* __restrict__ s0, const int* __restrict__ d0,
        const int* __restrict__ s1, const int* __restrict__ d1,
        const int* __restrict__ s2, const int* __restrict__ d2,
        int* __restrict__ cursor, int* __restrict__ ss2p) {
    __shared__ int hist[NB];
    __shared__ int lbase[NB];
    __shared__ int gbase[NB];
    __shared__ int stage_p[PART_E];
    __shared__ int stage_b[PART_E];
    __shared__ int wsum[4];
    __shared__ int s_vtot;

    const int tid = threadIdx.x;
    const int lane = tid & 63, wid = tid >> 6;
    for (int j = tid; j < NB; j += 256) hist[j] = 0;
    __syncthreads();

    const int e0 = blockIdx.x * PART_E;
    int myp[PART_E / 256], mybr[PART_E / 256];
    #pragma unroll
    for (int k = 0; k < PART_E / 256; ++k) {
        int i = e0 + k * 256 + tid;
        if (i < 3 * N_EDGE) {
            int r = (i >= 2 * N_EDGE) ? 2 : (i >= N_EDGE) ? 1 : 0;
            int e = i - r * N_EDGE;
            const int* sp = (r == 0) ? s0 : (r == 1) ? s1 : s2;
            const int* dp = (r == 0) ? d0 : (r == 1) ? d1 : d2;
            int d = dp[e];
            int bkt = d >> DSH;
            int rank = atomicAdd(&hist[bkt], 1);
            myp[k]  = sp[e] | ((d & (NDB - 1)) << 16) | (r << 22);
            mybr[k] = rank | (bkt << 12);
        } else {
            mybr[k] = -1;
        }
    }
    __syncthreads();

    {
        int vals[7]; int tsum = 0;
        int idx0 = tid * 7;
        #pragma unroll
        for (int k = 0; k < 7; ++k) {
            vals[k] = (idx0 + k < NB) ? hist[idx0 + k] : 0;
            tsum += vals[k];
        }
        int s = tsum;
        #pragma unroll
        for (int off = 1; off < 64; off <<= 1) {
            int t = __shfl_up(s, off);
            if (lane >= off) s += t;
        }
        if (lane == 63) wsum[wid] = s;
        __syncthreads();
        if (tid == 0) {
            int a = 0;
            #pragma unroll
            for (int j = 0; j < 4; ++j) { int t = wsum[j]; wsum[j] = a; a += t; }
        }
        __syncthreads();
        int run = (s - tsum) + wsum[wid];
        #pragma unroll
        for (int k = 0; k < 7; ++k) {
            if (idx0 + k < NB) lbase[idx0 + k] = run;
            run += vals[k];
        }
        if (tid == 255) s_vtot = run;
    }
    __syncthreads();

    for (int j = tid; j < NB; j += 256)
        if (hist[j] > 0) gbase[j] = atomicAdd(&cursor[j], hist[j]);
    __syncthreads();

    #pragma unroll
    for (int k = 0; k < PART_E / 256; ++k) {
        if (mybr[k] >= 0) {
            int bkt  = mybr[k] >> 12;
            int rank = mybr[k] & 0xFFF;
            int slot = lbase[bkt] + rank;
            stage_p[slot] = myp[k];
            stage_b[slot] = bkt;
        }
    }
    __syncthreads();

    const int vtot = s_vtot;
    for (int j = tid; j < vtot; j += 256) {
        int bkt = stage_b[j];
        ss2p[gbase[bkt] + (j - lbase[bkt])] = stage_p[j];
    }
}

// Fused in-LDS sort + register-accumulate gather. One block per 64-dst bucket.
// Half-wave hw owns dsts {hw, hw+8, ..., hw+56}; acc in registers (float4 x8).
// NO f32 atomics; int LDS atomics only for the histogram/cursors.
__global__ void __launch_bounds__(256) agg_kernel(
        const unsigned short* __restrict__ xb, const int* __restrict__ cbase,
        const int* __restrict__ ss2p, float* __restrict__ out) {
    __shared__ unsigned short sorted[CAP];   // 4 KB: src ids grouped by (r,dl)
    __shared__ int   hist [NK];              // total deg per (r,dl)
    __shared__ float scale[NK];
    __shared__ int   cnt  [NK];              // per-chunk count
    __shared__ int   start[NK];              // per-chunk segment start
    __shared__ int   cur  [NK];              // scatter cursor (-> segment end)

    const int tid  = threadIdx.x;
    const int lane = tid & 31;
    const int half = tid >> 5;               // 0..7
    const int b    = blockIdx.x;
    const int dbase = b << DSH;
    int dcount = N_VUL - dbase; if (dcount > NDB) dcount = NDB;

    const int beg = cbase[b];
    const int end = cbase[b + 1];

    // pass A: total per-(r,dl) degree -> scale
    for (int j = tid; j < NK; j += 256) hist[j] = 0;
    __syncthreads();
    for (int j = beg + tid; j < end; j += 256) {
        int p = ss2p[j];
        atomicAdd(&hist[((p >> 22) & 3) * NDB + ((p >> 16) & (NDB - 1))], 1);
    }
    __syncthreads();
    if (tid < NK) {
        int c = hist[tid];
        scale[tid] = 1.0f / (3.0f * (float)(c > 0 ? c : 1));
    }

    float4 acc[8];
    #pragma unroll
    for (int i = 0; i < 8; ++i) acc[i] = make_float4(0.f, 0.f, 0.f, 0.f);

    for (int cbeg = beg; cbeg < end; cbeg += CAP) {
        int cend = cbeg + CAP; if (cend > end) cend = end;
        int cn = cend - cbeg;

        for (int j = tid; j < NK; j += 256) cnt[j] = 0;
        __syncthreads();
        for (int j = tid; j < cn; j += 256) {
            int p = ss2p[cbeg + j];
            atomicAdd(&cnt[((p >> 22) & 3) * NDB + ((p >> 16) & (NDB - 1))], 1);
        }
        __syncthreads();

        // scan cnt[192] -> start (one wave, 3 entries/lane)
        if (tid < 64) {
            int v0 = cnt[tid * 3], v1 = cnt[tid * 3 + 1], v2 = cnt[tid * 3 + 2];
            int t = v0 + v1 + v2;
            int s = t;
            #pragma unroll
            for (int off = 1; off < 64; off <<= 1) {
                int u = __shfl_up(s, off);
                if (tid >= off) s += u;
            }
            int excl = s - t;
            start[tid * 3]     = excl;          cur[tid * 3]     = excl;
            start[tid * 3 + 1] = excl + v0;     cur[tid * 3 + 1] = excl + v0;
            start[tid * 3 + 2] = excl + v0 + v1; cur[tid * 3 + 2] = excl + v0 + v1;
        }
        __syncthreads();

        // scatter src ids into sorted[] via LDS int cursors
        for (int j = tid; j < cn; j += 256) {
            int p = ss2p[cbeg + j];
            int k = ((p >> 22) & 3) * NDB + ((p >> 16) & (NDB - 1));
            int pos = atomicAdd(&cur[k], 1);
            sorted[pos] = (unsigned short)(p & 0xFFFF);
        }
        __syncthreads();

        // gather: half-wave processes its 8 dsts' (r,dl) segments
        #pragma unroll
        for (int i = 0; i < 8; ++i) {
            int d = half + 8 * i;
            #pragma unroll
            for (int r = 0; r < 3; ++r) {
                int k  = r * NDB + d;
                int s0 = start[k];
                int s1 = cur[k];                 // segment end
                const unsigned short* xr = xb + (size_t)r * (N_SRC * DIM);
                float4 a = make_float4(0.f, 0.f, 0.f, 0.f);
                int j = s0;
                for (; j + 4 <= s1; j += 4) {
                    int sa = sorted[j], sb = sorted[j + 1];
                    int sc = sorted[j + 2], sd = sorted[j + 3];
                    ushort4 va = ((const ushort4*)(xr + (size_t)sa * DIM))[lane];
                    ushort4 vb = ((const ushort4*)(xr + (size_t)sb * DIM))[lane];
                    ushort4 vc = ((const ushort4*)(xr + (size_t)sc * DIM))[lane];
                    ushort4 vd = ((const ushort4*)(xr + (size_t)sd * DIM))[lane];
                    a.x += (bf2f(va.x) + bf2f(vb.x)) + (bf2f(vc.x) + bf2f(vd.x));
                    a.y += (bf2f(va.y) + bf2f(vb.y)) + (bf2f(vc.y) + bf2f(vd.y));
                    a.z += (bf2f(va.z) + bf2f(vb.z)) + (bf2f(vc.z) + bf2f(vd.z));
                    a.w += (bf2f(va.w) + bf2f(vb.w)) + (bf2f(vc.w) + bf2f(vd.w));
                }
                for (; j < s1; ++j) {
                    int sa = sorted[j];
                    ushort4 va = ((const ushort4*)(xr + (size_t)sa * DIM))[lane];
                    a.x += bf2f(va.x); a.y += bf2f(va.y);
                    a.z += bf2f(va.z); a.w += bf2f(va.w);
                }
                float sv = scale[k];
                acc[i].x += a.x * sv; acc[i].y += a.y * sv;
                acc[i].z += a.z * sv; acc[i].w += a.w * sv;
            }
        }
        __syncthreads();   // protect LDS before next chunk
    }

    // writeout: coalesced float4 per lane
    #pragma unroll
    for (int i = 0; i < 8; ++i) {
        int d = half + 8 * i;
        if (d < dcount)
            ((float4*)(out + (size_t)(dbase + d) * DIM))[lane] = acc[i];
    }
}

// ------------------------- TIER B / C kernels ------------------------------

__global__ void count3_kernel(const int* __restrict__ d0, const int* __restrict__ d1,
                              const int* __restrict__ d2, int* __restrict__ rp) {
    int i = blockIdx.x * blockDim.x + threadIdx.x;
    if (i >= 3 * N_EDGE) return;
    int r = (i >= 2 * N_EDGE) ? 2 : (i >= N_EDGE) ? 1 : 0;
    int e = i - r * N_EDGE;
    const int* d = (r == 0) ? d0 : (r == 1) ? d1 : d2;
    atomicAdd(&rp[r * N_VUL + d[e]], 1);
}

__global__ void scan_local_kernel(int* __restrict__ rp, int* __restrict__ bsum, int n) {
    __shared__ int wsum[4];
    const int tid  = threadIdx.x;
    const int lane = tid & 63;
    const int wid  = tid >> 6;
    int idx = blockIdx.x * 1024 + tid * 4;
    int4 v = make_int4(0, 0, 0, 0);
    if (idx + 3 < n)      v = *(const int4*)(rp + idx);
    else {
        if (idx + 0 < n) v.x = rp[idx + 0];
        if (idx + 1 < n) v.y = rp[idx + 1];
        if (idx + 2 < n) v.z = rp[idx + 2];
        if (idx + 3 < n) v.w = rp[idx + 3];
    }
    int tsum = v.x + v.y + v.z + v.w;
    int s = tsum;
    #pragma unroll
    for (int off = 1; off < 64; off <<= 1) {
        int t = __shfl_up(s, off);
        if (lane >= off) s += t;
    }
    if (lane == 63) wsum[wid] = s;
    __syncthreads();
    if (tid == 0) {
        int a = 0;
        #pragma unroll
        for (int j = 0; j < 4; ++j) { int t = wsum[j]; wsum[j] = a; a += t; }
        bsum[blockIdx.x] = a;
    }
    __syncthreads();
    int excl = (s - tsum) + wsum[wid];
    int4 o;
    o.x = excl; o.y = o.x + v.x; o.z = o.y + v.y; o.w = o.z + v.z;
    if (idx + 3 < n)      *(int4*)(rp + idx) = o;
    else {
        if (idx + 0 < n) rp[idx + 0] = o.x;
        if (idx + 1 < n) rp[idx + 1] = o.y;
        if (idx + 2 < n) rp[idx + 2] = o.z;
        if (idx + 3 < n) rp[idx + 3] = o.w;
    }
}

__global__ void scan_bsum_kernel(int* __restrict__ bsum, int nb) {
    __shared__ int sh[512];
    int tid = threadIdx.x;
    int v = (tid < nb) ? bsum[tid] : 0;
    sh[tid] = v;
    __syncthreads();
    #pragma unroll
    for (int off = 1; off < 512; off <<= 1) {
        int t = 0;
        if (tid >= off) t = sh[tid - off];
        __syncthreads();
        sh[tid] += t;
        __syncthreads();
    }
    if (tid < nb) bsum[tid] = sh[tid] - v;
}

__global__ void add_off_kernel(int4* __restrict__ rp4, const int* __restrict__ bsum, int n4) {
    int i = blockIdx.x * blockDim.x + threadIdx.x;
    if (i >= n4) return;
    int off = bsum[i >> 8];
    int4 v = rp4[i];
    v.x += off; v.y += off; v.z += off; v.w += off;
    rp4[i] = v;
}

__global__ void scatter3_kernel(const int* __restrict__ s0, const int* __restrict__ d0,
                                const int* __restrict__ s1, const int* __restrict__ d1,
                                const int* __restrict__ s2, const int* __restrict__ d2,
                                int* __restrict__ rp, int* __restrict__ ss) {
    int i = blockIdx.x * blockDim.x + threadIdx.x;
    if (i >= 3 * N_EDGE) return;
    int r = (i >= 2 * N_EDGE) ? 2 : (i >= N_EDGE) ? 1 : 0;
    int e = i - r * N_EDGE;
    const int* sp = (r == 0) ? s0 : (r == 1) ? s1 : s2;
    const int* dp = (r == 0) ? d0 : (r == 1) ? d1 : d2;
    int pos = atomicAdd(&rp[r * N_VUL + dp[e]], 1);
    ss[pos] = sp[e];
}

__global__ void gather3_kernel(const float* __restrict__ x0, const float* __restrict__ x1,
                               const float* __restrict__ x2,
                               const int* __restrict__ rp, const int* __restrict__ ss,
                               float* __restrict__ out) {
    int t    = blockIdx.x * blockDim.x + threadIdx.x;
    int v    = t >> 5;
    int lane = t & 31;
    if (v >= N_VUL) return;
    float4 res = make_float4(0.f, 0.f, 0.f, 0.f);
    #pragma unroll
    for (int r = 0; r < 3; ++r) {
        const float* x = (r == 0) ? x0 : (r == 1) ? x1 : x2;
        int g   = r * N_VUL + v;
        int end = rp[g];
        int beg = (g == 0) ? 0 : rp[g - 1];
        float4 acc = make_float4(0.f, 0.f, 0.f, 0.f);
        for (int base = beg; base < end; base += 32) {
            int j  = base + lane;
            int sv = (j < end) ? ss[j] : 0;
            int m  = end - base;
            if (m > 32) m = 32;
            for (int k = 0; k < m; ++k) {
                int s = __shfl(sv, k, 32);
                float4 xv = ((const float4*)(x + (size_t)s * DIM))[lane];
                acc.x += xv.x; acc.y += xv.y; acc.z += xv.z; acc.w += xv.w;
            }
        }
        int deg = end - beg;
        float sc = 1.0f / (3.0f * (float)(deg > 0 ? deg : 1));
        res.x += acc.x * sc; res.y += acc.y * sc;
        res.z += acc.z * sc; res.w += acc.w * sc;
    }
    ((float4*)(out + (size_t)v * DIM))[lane] = res;
}

__global__ void count_kernel(const int* __restrict__ dst, int* __restrict__ cnt, int n) {
    int i = blockIdx.x * blockDim.x + threadIdx.x;
    if (i < n) atomicAdd(&cnt[dst[i]], 1);
}

__global__ void scan_kernel(int* __restrict__ rp, int n) {
    __shared__ int warp_sums[16];
    __shared__ int s_carry;
    const int tid  = threadIdx.x;
    const int lane = tid & 63;
    const int wid  = tid >> 6;
    if (tid == 0) s_carry = 0;
    __syncthreads();
    for (int base = 0; base < n; base += 4096) {
        int idx = base + tid * 4;
        int4 v = make_int4(0, 0, 0, 0);
        if (idx + 3 < n) v = *(const int4*)(rp + idx);
        else {
            if (idx + 0 < n) v.x = rp[idx + 0];
            if (idx + 1 < n) v.y = rp[idx + 1];
            if (idx + 2 < n) v.z = rp[idx + 2];
            if (idx + 3 < n) v.w = rp[idx + 3];
        }
        int tsum = v.x + v.y + v.z + v.w;
        int s = tsum;
        #pragma unroll
        for (int off = 1; off < 64; off <<= 1) {
            int t = __shfl_up(s, off);
            if (lane >= off) s += t;
        }
        if (lane == 63) warp_sums[wid] = s;
        __syncthreads();
        if (tid < 16) {
            int ws = warp_sums[tid];
            #pragma unroll
            for (int off = 1; off < 16; off <<= 1) {
                int t = __shfl_up(ws, off);
                if (tid >= off) ws += t;
            }
            warp_sums[tid] = ws;
        }
        __syncthreads();
        int carry = s_carry;
        int excl  = s - tsum + (wid > 0 ? warp_sums[wid - 1] : 0) + carry;
        int4 o;
        o.x = excl; o.y = o.x + v.x; o.z = o.y + v.y; o.w = o.z + v.z;
        if (idx + 3 < n) *(int4*)(rp + idx) = o;
        else {
            if (idx + 0 < n) rp[idx + 0] = o.x;
            if (idx + 1 < n) rp[idx + 1] = o.y;
            if (idx + 2 < n) rp[idx + 2] = o.z;
            if (idx + 3 < n) rp[idx + 3] = o.w;
        }
        __syncthreads();
        if (tid == 0) s_carry = carry + warp_sums[15];
        __syncthreads();
    }
}

__global__ void scatter_kernel(const int* __restrict__ src, const int* __restrict__ dst,
                               int* __restrict__ rp, int* __restrict__ ss, int n) {
    int i = blockIdx.x * blockDim.x + threadIdx.x;
    if (i < n) {
        int pos = atomicAdd(&rp[dst[i]], 1);
        ss[pos] = src[i];
    }
}

template <bool ACC>
__global__ void gather_kernel(const float* __restrict__ x, const int* __restrict__ rp,
                              const int* __restrict__ ss, float* __restrict__ out) {
    int t    = blockIdx.x * blockDim.x + threadIdx.x;
    int v    = t >> 5;
    int lane = t & 31;
    if (v >= N_VUL) return;
    int end = rp[v];
    int beg = (v == 0) ? 0 : rp[v - 1];
    float4 acc = make_float4(0.f, 0.f, 0.f, 0.f);
    for (int base = beg; base < end; base += 32) {
        int j  = base + lane;
        int sv = (j < end) ? ss[j] : 0;
        int m  = end - base;
        if (m > 32) m = 32;
        for (int k = 0; k < m; ++k) {
            int s = __shfl(sv, k, 32);
            float4 xv = ((const float4*)(x + (size_t)s * DIM))[lane];
            acc.x += xv.x; acc.y += xv.y; acc.z += xv.z; acc.w += xv.w;
        }
    }
    int deg = end - beg;
    float sc = 1.0f / (3.0f * (float)(deg > 0 ? deg : 1));
    float4 res;
    res.x = acc.x * sc; res.y = acc.y * sc; res.z = acc.z * sc; res.w = acc.w * sc;
    float4* o = (float4*)(out + (size_t)v * DIM) + lane;
    if (ACC) {
        float4 prev = *o;
        res.x += prev.x; res.y += prev.y; res.z += prev.z; res.w += prev.w;
    }
    *o = res;
}

// ---------------------------------------------------------------------------
extern "C" void kernel_launch(void* const* d_in, const int* in_sizes, int n_in,
                              void* d_out, int out_size, void* d_ws, size_t ws_size,
                              hipStream_t stream) {
    const float* x[3]   = { (const float*)d_in[0], (const float*)d_in[1], (const float*)d_in[2] };
    const int*   src[3] = { (const int*)d_in[3],   (const int*)d_in[5],   (const int*)d_in[7] };
    const int*   dst[3] = { (const int*)d_in[4],   (const int*)d_in[6],   (const int*)d_in[8] };
    float* out = (float*)d_out;

    const int B = 256;
    const int n_rp     = 3 * N_VUL;
    const int n_chunks = (n_rp + 1023) / 1024;
    const int n_rp4    = n_rp / 4;

    // Tier S layout (ints): gcount@0 | cbase@2048 | cursor@4096 | ss2p@6144 | xb
    const size_t S_INTS = 6144 + (size_t)3 * N_EDGE;
    const size_t S_WS   = S_INTS * 4 + (size_t)3 * N_SRC * DIM * sizeof(short);  // ~44.4 MB
    const size_t INT_WS = (size_t)(n_rp + 3 * N_EDGE + 512) * sizeof(int);       // 7.2 MB

    if (ws_size >= S_WS) {
        int* gcount = (int*)d_ws;
        int* cbase  = gcount + 2048;
        int* cursor = gcount + 4096;
        int* ss2p   = gcount + 6144;
        unsigned short* xb = (unsigned short*)(ss2p + 3 * N_EDGE);

        zero_i_kernel<<<(NB + B - 1) / B, B, 0, stream>>>(gcount, NB);
        cvt_chist_kernel<<<CVT_BLOCKS + PART_BLOCKS, B, 0, stream>>>(
            (const float4*)x[0], (const float4*)x[1], (const float4*)x[2], (ushort4*)xb,
            dst[0], dst[1], dst[2], gcount);
        cscan_kernel<<<1, B, 0, stream>>>(gcount, cbase, cursor);
        partition_kernel<<<PART_BLOCKS, B, 0, stream>>>(
            src[0], dst[0], src[1], dst[1], src[2], dst[2], cursor, ss2p);
        agg_kernel<<<NB, B, 0, stream>>>(xb, cbase, ss2p, out);
    } else if (ws_size >= INT_WS) {
        int* rp   = (int*)d_ws;
        int* ss   = rp + n_rp;
        int* bsum = ss + 3 * N_EDGE;

        zero_i_kernel<<<(n_rp + B - 1) / B, B, 0, stream>>>(rp, n_rp);
        count3_kernel<<<(3 * N_EDGE + B - 1) / B, B, 0, stream>>>(dst[0], dst[1], dst[2], rp);
        scan_local_kernel<<<n_chunks, B, 0, stream>>>(rp, bsum, n_rp);
        scan_bsum_kernel<<<1, 512, 0, stream>>>(bsum, n_chunks);
        add_off_kernel<<<(n_rp4 + B - 1) / B, B, 0, stream>>>((int4*)rp, bsum, n_rp4);
        scatter3_kernel<<<(3 * N_EDGE + B - 1) / B, B, 0, stream>>>(
            src[0], dst[0], src[1], dst[1], src[2], dst[2], rp, ss);
        gather3_kernel<<<(N_VUL * 32 + B - 1) / B, B, 0, stream>>>(
            x[0], x[1], x[2], rp, ss, out);
    } else {
        int* rp = (int*)d_ws;
        int* ss = rp + N_VUL;
        const int g_node = (N_VUL + B - 1) / B;
        const int g_edge = (N_EDGE + B - 1) / B;
        const int g_gath = (N_VUL * 32 + B - 1) / B;
        for (int r = 0; r < 3; ++r) {
            zero_i_kernel<<<g_node, B, 0, stream>>>(rp, N_VUL);
            count_kernel<<<g_edge, B, 0, stream>>>(dst[r], rp, N_EDGE);
            scan_kernel<<<1, 1024, 0, stream>>>(rp, N_VUL);
            scatter_kernel<<<g_edge, B, 0, stream>>>(src[r], dst[r], rp, ss, N_EDGE);
            if (r == 0) gather_kernel<false><<<g_gath, B, 0, stream>>>(x[r], rp, ss, out);
            else        gather_kernel<true ><<<g_gath, B, 0, stream>>>(x[r], rp, ss, out);
        }
    }
}